// Round 10
// baseline (687.387 us; speedup 1.0000x reference)
//
#include <hip/hip_runtime.h>

#define N_NODES 50000
#define N_EDGES 800000
#define DIM 128
#define NLAYERS 4
#define BN_EPS 1e-5f
#define SCAN_BLOCKS 196   // ceil(N_NODES/256)
#define WS2 72            // 64 + 8 bf16 pad (k-half stride, bank decorrelation)

typedef __attribute__((ext_vector_type(8))) short short8;
typedef __attribute__((ext_vector_type(4))) float f32x4;

__device__ __forceinline__ float bf2f(unsigned short u){
    union { unsigned int i; float f; } x; x.i = ((unsigned int)u) << 16; return x.f;
}
__device__ __forceinline__ unsigned short f2bf(float f){
    union { float f; unsigned int i; } x; x.f = f;
    unsigned int lsb = (x.i >> 16) & 1u;
    unsigned int r = x.i + 0x7fffu + lsb;
    return (unsigned short)(r >> 16);
}

// ---------------- prep kernels ----------------

__global__ __launch_bounds__(256) void k_zero(int* __restrict__ p, int n){
    int i = blockIdx.x * 256 + threadIdx.x;
    if (i < n) p[i] = 0;
}

__global__ __launch_bounds__(256) void k_count(const int* __restrict__ dst,
                                               int* __restrict__ degcnt){
    int e = blockIdx.x * 256 + threadIdx.x;
    if (e < N_EDGES) atomicAdd(&degcnt[dst[e]], 1);
}

// phase 1 + dis: per-block exclusive scan of degcnt; also dis = rsqrt(deg+1)
__global__ __launch_bounds__(256) void k_scan1(const int* __restrict__ degcnt,
                                               int* __restrict__ rowptr,
                                               int* __restrict__ bsum,
                                               float* __restrict__ dis){
    __shared__ int tmp[256];
    int t = threadIdx.x;
    int i = blockIdx.x * 256 + t;
    int v = (i < N_NODES) ? degcnt[i] : 0;
    if (i < N_NODES) dis[i] = rsqrtf((float)v + 1.0f);
    tmp[t] = v;
    __syncthreads();
    #pragma unroll
    for (int off = 1; off < 256; off <<= 1){
        int u = (t >= off) ? tmp[t - off] : 0;
        __syncthreads();
        tmp[t] += u;
        __syncthreads();
    }
    if (i < N_NODES) rowptr[i] = tmp[t] - v;
    if (t == 255) bsum[blockIdx.x] = tmp[255];
}

// scan3 with scan2 folded in: each block scans bsum itself and applies offset
__global__ __launch_bounds__(256) void k_scan3(const int* __restrict__ bsum,
                                               int* __restrict__ rowptr,
                                               int* __restrict__ wptr){
    __shared__ int tmp[256];
    int t = threadIdx.x;
    int v = (t < SCAN_BLOCKS) ? bsum[t] : 0;
    tmp[t] = v;
    __syncthreads();
    #pragma unroll
    for (int off = 1; off < 256; off <<= 1){
        int u = (t >= off) ? tmp[t - off] : 0;
        __syncthreads();
        tmp[t] += u;
        __syncthreads();
    }
    int boff = (blockIdx.x == 0) ? 0 : tmp[blockIdx.x - 1];  // exclusive
    int i = blockIdx.x * 256 + t;
    if (i < N_NODES){
        int r = rowptr[i] + boff;
        rowptr[i] = r; wptr[i] = r;
    }
    if (i == 0) rowptr[N_NODES] = N_EDGES;
}

// epair.x stores PRE-SHIFTED byte offset (s << 6 = s*64B line in a group slice)
__global__ __launch_bounds__(256) void k_fill(const int* __restrict__ src,
                                              const int* __restrict__ dst,
                                              const float* __restrict__ dis,
                                              int* __restrict__ wptr,
                                              int2* __restrict__ epair){
    int e = blockIdx.x * 256 + threadIdx.x;
    if (e < N_EDGES){
        int s = src[e], d = dst[e];
        float w = dis[s] * dis[d];
        int p = atomicAdd(&wptr[d], 1);
        int2 pr; pr.x = s << 6; pr.y = __float_as_int(w);
        epair[p] = pr;
    }
}

// ---------------- per-layer kernels ----------------
// Grouped feature layout: t[g][node][32 cols], g = col>>5 (3.2MB/slice).

// Per-layer W prep (runs ONCE per layer instead of per gemm-block):
//   whip/wlop: bf16 hi/lo of diag(sc)*W, stored in gemm LDS order:
//     [half][c][kk]  (half = k>>6, kk = k&63), 8192 shorts per half.
//   b2g: (beta - mu*sc) @ W  (zero for layer 0).
// Blocks 0..15 convert 1024 elems each; block 16 computes b2.
template<int MODE>
__global__ __launch_bounds__(256) void k_wprep(const float* __restrict__ W,
                                               const float* __restrict__ stats,
                                               const float* __restrict__ gamma,
                                               const float* __restrict__ beta,
                                               short* __restrict__ whip,
                                               short* __restrict__ wlop,
                                               float* __restrict__ b2g){
    __shared__ float scs[DIM], shs[DIM];
    __shared__ float part[256];
    int tid = threadIdx.x;
    if (MODE == 1){
        if (tid < DIM){
            float mu  = stats[tid] * (1.0f / N_NODES);
            float var = stats[DIM + tid] * (1.0f / N_NODES) - mu * mu;
            float sc  = rsqrtf(var + BN_EPS) * gamma[tid];
            scs[tid] = sc;
            shs[tid] = beta[tid] - mu * sc;
        }
        __syncthreads();
    }
    if (blockIdx.x < 16){
        // src-contiguous: j = elem index in row-major W
        int j = blockIdx.x * 1024 + tid * 4;
        int k = j >> 7;            // W row (K index)
        int c0 = j & 127;          // 4 consecutive cols
        float4 wv = *(const float4*)(W + k*DIM + c0);
        float sc = (MODE == 1) ? scs[k] : 1.0f;
        float v[4] = {wv.x*sc, wv.y*sc, wv.z*sc, wv.w*sc};
        int h = k >> 6, kk = k & 63;
        #pragma unroll
        for (int i = 0; i < 4; i++){
            unsigned short hi = f2bf(v[i]);
            float lo = v[i] - bf2f(hi);
            int d = h*8192 + (c0 + i)*64 + kk;
            whip[d] = (short)hi;
            wlop[d] = (short)f2bf(lo);
        }
    } else {
        if (MODE == 0){
            if (tid < DIM) b2g[tid] = 0.f;
        } else {
            int c = tid >> 1, hf = tid & 1;
            float acc = 0.f;
            int k0 = hf * 64;
            #pragma unroll 4
            for (int k = k0; k < k0 + 64; k++)
                acc = fmaf(shs[k], W[k*DIM + c], acc);
            part[tid] = acc;
            __syncthreads();
            if (tid < DIM) b2g[tid] = part[2*tid] + part[2*tid + 1];
        }
    }
}

// MFMA GEMM, W pre-converted by k_wprep. Stage = pure vector copy (8x16B
// loads + 8 LDS writes/thread per half). MODE 0: A = x fp32 std layout.
// MODE 1: A = grouped bf16 (BN fold already inside whip/wlop/b2g).
// 64 rows/block, 4 waves; wave = 16 rows x 128 cols = 8 mfma 16x16x32, K=128.
template<int MODE>
__global__ __launch_bounds__(256) void k_gemm(const void* __restrict__ zraw,
                                              const short* __restrict__ whip,
                                              const short* __restrict__ wlop,
                                              const float* __restrict__ b2g,
                                              unsigned short* __restrict__ hb){
    __shared__ short whi[DIM * WS2];           // 18432 B (k-half, all 128 cols)
    __shared__ short wlo[DIM * WS2];           // 18432 B
    __shared__ float b2s[DIM];
    int tid = threadIdx.x;

    int lane = tid & 63;
    int wv   = tid >> 6;
    int m = lane & 15;
    int q = lane >> 4;
    int row0 = blockIdx.x * 64 + wv * 16;
    int arow = row0 + m;
    bool avalid = arow < N_NODES;

    f32x4 acc[8];
    #pragma unroll
    for (int t = 0; t < 8; t++) acc[t] = (f32x4){0.f, 0.f, 0.f, 0.f};

    int cs = tid >> 1, pp = tid & 1;           // stage coords: row, 32-short half

    #pragma unroll
    for (int half = 0; half < 2; half++){
        {
            const short8* sh_ = (const short8*)(whip + half*8192 + cs*64 + pp*32);
            const short8* sl_ = (const short8*)(wlop + half*8192 + cs*64 + pp*32);
            short8* dh = (short8*)&whi[cs*WS2 + pp*32];
            short8* dl = (short8*)&wlo[cs*WS2 + pp*32];
            dh[0] = sh_[0]; dh[1] = sh_[1]; dh[2] = sh_[2]; dh[3] = sh_[3];
            dl[0] = sl_[0]; dl[1] = sl_[1]; dl[2] = sl_[2]; dl[3] = sl_[3];
            if (half == 0 && tid < DIM) b2s[tid] = b2g[tid];
        }
        __syncthreads();

        #pragma unroll
        for (int gl2 = 0; gl2 < 2; gl2++){     // local group within half
            int gg = half*2 + gl2;             // global feature group
            short8 a = {0,0,0,0,0,0,0,0};
            if (avalid){
                if (MODE == 0){
                    const float* xp = (const float*)zraw + (size_t)arow*DIM + gg*32 + q*8;
                    float4 v0 = *(const float4*)xp;
                    float4 v1 = *(const float4*)(xp + 4);
                    a[0] = (short)f2bf(v0.x); a[1] = (short)f2bf(v0.y);
                    a[2] = (short)f2bf(v0.z); a[3] = (short)f2bf(v0.w);
                    a[4] = (short)f2bf(v1.x); a[5] = (short)f2bf(v1.y);
                    a[6] = (short)f2bf(v1.z); a[7] = (short)f2bf(v1.w);
                } else {
                    a = *(const short8*)((const unsigned short*)zraw
                          + (size_t)gg*N_NODES*32 + (size_t)arow*32 + q*8);
                }
            }
            #pragma unroll
            for (int t = 0; t < 8; t++){
                int col = t*16 + m;
                int off = col*WS2 + gl2*32 + q*8;
                short8 bh = *(const short8*)&whi[off];
                short8 bl = *(const short8*)&wlo[off];
                acc[t] = __builtin_amdgcn_mfma_f32_16x16x32_bf16(a, bh, acc[t], 0, 0, 0);
                acc[t] = __builtin_amdgcn_mfma_f32_16x16x32_bf16(a, bl, acc[t], 0, 0, 0);
            }
        }
        if (half == 0) __syncthreads();        // drain reads before restage
    }

    #pragma unroll
    for (int t = 0; t < 8; t++){
        int colg = t*16 + m;
        float bz = b2s[colg];
        size_t base = (size_t)(t >> 1)*N_NODES*32 + (t & 1)*16 + m;
        #pragma unroll
        for (int r = 0; r < 4; r++){
            int row = row0 + q*4 + r;
            if (row < N_NODES)
                hb[base + (size_t)row*32] = f2bf(acc[t][r] + bz);
        }
    }
}

// CSR aggregation + bias + ReLU + per-column stats, feature-group partitioned.
// DWORDX4 GATHERS: lane = (edge slot j = lane>>2, 16B segment s4 = lane&3).
// One 16-edge chunk = 1 epair VMEM + 1 gather VMEM (was 4+4); each lane owns
// its edge's weight directly (no broadcast); per-edge address work /4.
// Node-end reduce: 4 shfl_xor rounds (4,8,16,32) x 8 accs; j==0 lanes apply
// self-term+bias+relu, store one uint4 (64B row via 4 lanes), track stats.
__global__ __launch_bounds__(256) void k_agg(const unsigned short* __restrict__ h,
                                             const int* __restrict__ rowptr,
                                             const int2* __restrict__ epair,
                                             const float* __restrict__ dis,
                                             const float* __restrict__ bias,
                                             unsigned short* __restrict__ out,
                                             float* __restrict__ stats){
    int lane = threadIdx.x & 63;
    int w    = threadIdx.x >> 6;
    int g    = blockIdx.x & 3;
    int j    = lane >> 2;          // edge slot 0..15
    int s4   = lane & 3;           // 16B segment (8 cols)
    const char* hgb = (const char*)(h + (size_t)g * N_NODES * 32);
    char* ogb = (char*)(out + (size_t)g * N_NODES * 32);
    float4 bA = *(const float4*)(bias + g*32 + s4*8);
    float4 bB = *(const float4*)(bias + g*32 + s4*8 + 4);
    float bl[8] = {bA.x, bA.y, bA.z, bA.w, bB.x, bB.y, bB.z, bB.w};
    float st_s[8] = {0,0,0,0,0,0,0,0};
    float st_q[8] = {0,0,0,0,0,0,0,0};
    int bg = blockIdx.x >> 2;
    int nstride = (gridDim.x >> 2) * 4;

    int node = bg*4 + w;
    int e0 = 0, e1 = 0; float di = 0.f;
    if (node < N_NODES){ e0 = rowptr[node]; e1 = rowptr[node+1]; di = dis[node]; }

    while (node < N_NODES){
        int nn = node + nstride;
        int ne0 = 0, ne1 = 0; float ndi = 0.f;
        if (nn < N_NODES){ ne0 = rowptr[nn]; ne1 = rowptr[nn+1]; ndi = dis[nn]; }

        float acc[8] = {0,0,0,0,0,0,0,0};
        for (int e = e0; e < e1; e += 16){
            int idx = e + j;
            if (idx < e1){
                int2 pe = epair[idx];
                float we = __int_as_float(pe.y);
                uint4 xv = *(const uint4*)(hgb + pe.x + s4*16);
                unsigned u0 = xv.x, u1 = xv.y, u2 = xv.z, u3 = xv.w;
                acc[0] = fmaf(__uint_as_float(u0 << 16),          we, acc[0]);
                acc[1] = fmaf(__uint_as_float(u0 & 0xffff0000u),  we, acc[1]);
                acc[2] = fmaf(__uint_as_float(u1 << 16),          we, acc[2]);
                acc[3] = fmaf(__uint_as_float(u1 & 0xffff0000u),  we, acc[3]);
                acc[4] = fmaf(__uint_as_float(u2 << 16),          we, acc[4]);
                acc[5] = fmaf(__uint_as_float(u2 & 0xffff0000u),  we, acc[5]);
                acc[6] = fmaf(__uint_as_float(u3 << 16),          we, acc[6]);
                acc[7] = fmaf(__uint_as_float(u3 & 0xffff0000u),  we, acc[7]);
            }
        }

        // reduce over edge slots: lanes sharing s4 differ in bits [5:2]
        #pragma unroll
        for (int m2 = 4; m2 <= 32; m2 <<= 1){
            #pragma unroll
            for (int k = 0; k < 8; k++)
                acc[k] += __shfl_xor(acc[k], m2);
        }

        if (j == 0){
            uint4 hv = *(const uint4*)(hgb + (size_t)node*64 + s4*16);
            float dii = di * di;
            unsigned hu[4] = {hv.x, hv.y, hv.z, hv.w};
            unsigned ov[4];
            #pragma unroll
            for (int k = 0; k < 4; k++){
                float a0 = fmaf(__uint_as_float(hu[k] << 16),         dii, acc[2*k])   + bl[2*k];
                float a1 = fmaf(__uint_as_float(hu[k] & 0xffff0000u), dii, acc[2*k+1]) + bl[2*k+1];
                a0 = fmaxf(a0, 0.f); a1 = fmaxf(a1, 0.f);
                st_s[2*k] += a0;     st_s[2*k+1] += a1;
                st_q[2*k] += a0*a0;  st_q[2*k+1] += a1*a1;
                ov[k] = ((unsigned)f2bf(a1) << 16) | (unsigned)f2bf(a0);
            }
            uint4 o4; o4.x = ov[0]; o4.y = ov[1]; o4.z = ov[2]; o4.w = ov[3];
            *(uint4*)(ogb + (size_t)node*64 + s4*16) = o4;
        }

        e0 = ne0; e1 = ne1; di = ndi; node = nn;
    }

    // stats: LDS reduce across 4 waves, then 64 atomics/block
    __shared__ float red[4][4][16];   // [wave][s4][8 sums | 8 sqs]
    if (j == 0){
        #pragma unroll
        for (int k = 0; k < 8; k++){
            red[w][s4][k]     = st_s[k];
            red[w][s4][8 + k] = st_q[k];
        }
    }
    __syncthreads();
    int t = threadIdx.x;
    if (t < 64){
        int sseg = t >> 4;             // s4
        int isq  = (t >> 3) & 1;
        int kk   = t & 7;
        int e16  = (isq << 3) + kk;
        float v = red[0][sseg][e16] + red[1][sseg][e16]
                + red[2][sseg][e16] + red[3][sseg][e16];
        atomicAdd(&stats[isq*DIM + g*32 + sseg*8 + kk], v);
    }
}

// final-layer BN apply: grouped bf16 in -> standard-layout fp32 out.
// scsh computed in-kernel from stats/gamma/beta.
__global__ __launch_bounds__(256) void k_bn(const uint4* __restrict__ in,
                                            const float* __restrict__ stats,
                                            const float* __restrict__ gamma,
                                            const float* __restrict__ beta,
                                            float4* __restrict__ outf){
    __shared__ float scs[DIM], shs[DIM];
    int tid = threadIdx.x;
    if (tid < DIM){
        float mu  = stats[tid] * (1.0f / N_NODES);
        float var = stats[DIM + tid] * (1.0f / N_NODES) - mu * mu;
        float sc  = rsqrtf(var + BN_EPS) * gamma[tid];
        scs[tid] = sc;
        shs[tid] = beta[tid] - mu * sc;
    }
    __syncthreads();

    int i = blockIdx.x * 256 + tid;                 // 8-bf16 chunk index
    if (i >= N_NODES * DIM / 8) return;
    int row = i >> 4;
    int c = (i * 8) & (DIM - 1);
    int gg = c >> 5, wi = c & 31;
    uint4 raw = in[gg*(N_NODES*4) + row*4 + (wi >> 3)];
    unsigned int u[4] = {raw.x, raw.y, raw.z, raw.w};
    float v[8];
    #pragma unroll
    for (int j = 0; j < 4; j++){
        v[2*j]   = bf2f((unsigned short)(u[j] & 0xffff));
        v[2*j+1] = bf2f((unsigned short)(u[j] >> 16));
    }
    float4 r0, r1;
    r0.x = fmaf(v[0], scs[c+0], shs[c+0]);
    r0.y = fmaf(v[1], scs[c+1], shs[c+1]);
    r0.z = fmaf(v[2], scs[c+2], shs[c+2]);
    r0.w = fmaf(v[3], scs[c+3], shs[c+3]);
    r1.x = fmaf(v[4], scs[c+4], shs[c+4]);
    r1.y = fmaf(v[5], scs[c+5], shs[c+5]);
    r1.z = fmaf(v[6], scs[c+6], shs[c+6]);
    r1.w = fmaf(v[7], scs[c+7], shs[c+7]);
    outf[2*i]   = r0;
    outf[2*i+1] = r1;
}

// ---------------- launch ----------------

extern "C" void kernel_launch(void* const* d_in, const int* in_sizes, int n_in,
                              void* d_out, int out_size, void* d_ws, size_t ws_size,
                              hipStream_t stream){
    const float* x   = (const float*)d_in[0];
    const int*   src = (const int*)d_in[1];
    const int*   dst = src + N_EDGES;
    const float* Ws  = (const float*)d_in[2];
    const float* bs  = (const float*)d_in[3];
    const float* gs  = (const float*)d_in[4];
    const float* be  = (const float*)d_in[5];

    char* w = (char*)d_ws;
    int*   degcnt = (int*)(w);                         // 50000 i  [0,200000)
    // wprep buffers overlap the degcnt region (degcnt dead after k_scan1;
    // k_zero re-zeroes it each iteration BEFORE any wprep runs).
    short* whip   = (short*)(w);                       // 32768 B
    short* wlop   = (short*)(w + 32768);               // 32768 B
    float* b2g    = (float*)(w + 65536);               // 512 B (< degcnt 200KB)
    float* stats  = (float*)(w + 200000);              // 1024 f
    float* dis    = (float*)(w + 208192);              // 50000 f
    int*   rowptr = (int*)(w + 408192);                // 50001 i (pad)
    int*   wptr   = (int*)(w + 608208);                // 50000 i
    int*   bsum   = (int*)(w + 808208);                // 196 i (pad)
    int2*  epair  = (int2*)(w + 875280);               // 800000 int2 (6.4MB)
    unsigned short* bufA = (unsigned short*)(w + 7275280);   // grouped bf16 (12.8MB)
    unsigned short* hb   = (unsigned short*)(w + 20075280);  // grouped bf16 (12.8MB)
    // total: 32,875,280 bytes

    k_zero<<<(51024 + 255)/256, 256, 0, stream>>>(degcnt, 51024);
    k_count<<<3125, 256, 0, stream>>>(dst, degcnt);
    k_scan1<<<SCAN_BLOCKS, 256, 0, stream>>>(degcnt, rowptr, bsum, dis);
    k_scan3<<<SCAN_BLOCKS, 256, 0, stream>>>(bsum, rowptr, wptr);
    k_fill<<<3125, 256, 0, stream>>>(src, dst, dis, wptr, epair);

    for (int L = 0; L < NLAYERS; L++){
        const float* Wl = Ws + L*DIM*DIM;
        if (L == 0){
            k_wprep<0><<<17, 256, 0, stream>>>(Wl, nullptr, nullptr, nullptr,
                                               whip, wlop, b2g);
            k_gemm<0><<<(N_NODES + 63)/64, 256, 0, stream>>>(x, whip, wlop,
                                               b2g, hb);
        } else {
            k_wprep<1><<<17, 256, 0, stream>>>(Wl, stats + (L-1)*256,
                                               gs + (L-1)*DIM, be + (L-1)*DIM,
                                               whip, wlop, b2g);
            k_gemm<1><<<(N_NODES + 63)/64, 256, 0, stream>>>(bufA, whip, wlop,
                                               b2g, hb);
        }
        k_agg<<<2048, 256, 0, stream>>>(hb, rowptr, epair, dis, bs + L*DIM,
                                        bufA, stats + L*256);
    }
    k_bn<<<3125, 256, 0, stream>>>((const uint4*)bufA, stats + 3*256,
                                   gs + 3*DIM, be + 3*DIM, (float4*)d_out);
}

// Round 13
// 548.093 us; speedup vs baseline: 1.2541x; 1.2541x over previous
//
#include <hip/hip_runtime.h>

#define N_NODES 50000
#define N_EDGES 800000
#define DIM 128
#define NLAYERS 4
#define BN_EPS 1e-5f
#define SCAN_BLOCKS 196
#define WS2 72

typedef __attribute__((ext_vector_type(8))) short short8;
typedef __attribute__((ext_vector_type(4))) float f32x4;

__device__ __forceinline__ float bf2f(unsigned short u){
    union { unsigned int i; float f; } x; x.i = ((unsigned int)u) << 16; return x.f;
}
__device__ __forceinline__ unsigned short f2bf(float f){
    union { float f; unsigned int i; } x; x.f = f;
    unsigned int lsb = (x.i >> 16) & 1u;
    unsigned int r = x.i + 0x7fffu + lsb;
    return (unsigned short)(r >> 16);
}

struct P4 { int2 a, b, c, d; };

__device__ __forceinline__ P4 loadP_mask(const int2* __restrict__ ep, int base,
                                         int sub, int lim){
    P4 p;
    int i0 = base + sub, i1 = base + 4 + sub, i2 = base + 8 + sub, i3 = base + 12 + sub;
    p.a = (i0 < lim) ? ep[i0] : make_int2(0, 0);
    p.b = (i1 < lim) ? ep[i1] : make_int2(0, 0);
    p.c = (i2 < lim) ? ep[i2] : make_int2(0, 0);
    p.d = (i3 < lim) ? ep[i3] : make_int2(0, 0);
    return p;
}
__device__ __forceinline__ P4 loadP_full(const int2* __restrict__ ep, int base,
                                         int sub){
    P4 p;
    p.a = ep[base + sub];
    p.b = ep[base + 4 + sub];
    p.c = ep[base + 8 + sub];
    p.d = ep[base + 12 + sub];
    return p;
}
__device__ __forceinline__ P4 loadP(const int2* __restrict__ ep, int base,
                                    int sub, int lim){
    if (lim - base >= 16) return loadP_full(ep, base, sub);
    return loadP_mask(ep, base, sub, lim);
}

__global__ __launch_bounds__(256) void k_zero(int* __restrict__ p, int n){
    int i = blockIdx.x * 256 + threadIdx.x;
    if (i < n) p[i] = 0;
}

__global__ __launch_bounds__(256) void k_count(const int* __restrict__ dst,
                                               int* __restrict__ degcnt){
    int e = blockIdx.x * 256 + threadIdx.x;
    if (e < N_EDGES) atomicAdd(&degcnt[dst[e]], 1);
}

__global__ __launch_bounds__(256) void k_scan1(const int* __restrict__ degcnt,
                                               int* __restrict__ rowptr,
                                               int* __restrict__ bsum,
                                               float* __restrict__ dis){
    __shared__ int tmp[256];
    int t = threadIdx.x;
    int i = blockIdx.x * 256 + t;
    int v = (i < N_NODES) ? degcnt[i] : 0;
    if (i < N_NODES) dis[i] = rsqrtf((float)v + 1.0f);
    tmp[t] = v;
    __syncthreads();
    #pragma unroll
    for (int off = 1; off < 256; off <<= 1){
        int u = (t >= off) ? tmp[t - off] : 0;
        __syncthreads();
        tmp[t] += u;
        __syncthreads();
    }
    if (i < N_NODES) rowptr[i] = tmp[t] - v;
    if (t == 255) bsum[blockIdx.x] = tmp[255];
}

__global__ __launch_bounds__(256) void k_scan3(const int* __restrict__ bsum,
                                               int* __restrict__ rowptr,
                                               int* __restrict__ wptr){
    __shared__ int tmp[256];
    int t = threadIdx.x;
    int v = (t < SCAN_BLOCKS) ? bsum[t] : 0;
    tmp[t] = v;
    __syncthreads();
    #pragma unroll
    for (int off = 1; off < 256; off <<= 1){
        int u = (t >= off) ? tmp[t - off] : 0;
        __syncthreads();
        tmp[t] += u;
        __syncthreads();
    }
    int boff = (blockIdx.x == 0) ? 0 : tmp[blockIdx.x - 1];
    int i = blockIdx.x * 256 + t;
    if (i < N_NODES){
        int r = rowptr[i] + boff;
        rowptr[i] = r; wptr[i] = r;
    }
    if (i == 0) rowptr[N_NODES] = N_EDGES;
}

__global__ __launch_bounds__(256) void k_fill(const int* __restrict__ src,
                                              const int* __restrict__ dst,
                                              const float* __restrict__ dis,
                                              int* __restrict__ wptr,
                                              int2* __restrict__ epair){
    int e = blockIdx.x * 256 + threadIdx.x;
    if (e < N_EDGES){
        int s = src[e], d = dst[e];
        float w = dis[s] * dis[d];
        int p = atomicAdd(&wptr[d], 1);
        int2 pr; pr.x = s << 6; pr.y = __float_as_int(w);
        epair[p] = pr;
    }
}

template<int MODE>
__global__ __launch_bounds__(256) void k_wprep(const float* __restrict__ W,
                                               const float* __restrict__ stats,
                                               const float* __restrict__ gamma,
                                               const float* __restrict__ beta,
                                               short* __restrict__ whip,
                                               short* __restrict__ wlop,
                                               float* __restrict__ b2g){
    __shared__ float scs[DIM], shs[DIM];
    __shared__ float part[256];
    int tid = threadIdx.x;
    if (MODE == 1){
        if (tid < DIM){
            float mu  = stats[tid] * (1.0f / N_NODES);
            float var = stats[DIM + tid] * (1.0f / N_NODES) - mu * mu;
            float sc  = rsqrtf(var + BN_EPS) * gamma[tid];
            scs[tid] = sc;
            shs[tid] = beta[tid] - mu * sc;
        }
        __syncthreads();
    }
    if (blockIdx.x < 16){
        int j = blockIdx.x * 1024 + tid * 4;
        int k = j >> 7;
        int c0 = j & 127;
        float4 wv = *(const float4*)(W + k*DIM + c0);
        float sc = (MODE == 1) ? scs[k] : 1.0f;
        float v[4] = {wv.x*sc, wv.y*sc, wv.z*sc, wv.w*sc};
        int h = k >> 6, kk = k & 63;
        #pragma unroll
        for (int i = 0; i < 4; i++){
            unsigned short hi = f2bf(v[i]);
            float lo = v[i] - bf2f(hi);
            int d = h*8192 + (c0 + i)*64 + kk;
            whip[d] = (short)hi;
            wlop[d] = (short)f2bf(lo);
        }
    } else {
        if (MODE == 0){
            if (tid < DIM) b2g[tid] = 0.f;
        } else {
            int c = tid >> 1, hf = tid & 1;
            float acc = 0.f;
            int k0 = hf * 64;
            #pragma unroll 4
            for (int k = k0; k < k0 + 64; k++)
                acc = fmaf(shs[k], W[k*DIM + c], acc);
            part[tid] = acc;
            __syncthreads();
            if (tid < DIM) b2g[tid] = part[2*tid] + part[2*tid + 1];
        }
    }
}

template<int MODE>
__global__ __launch_bounds__(256) void k_gemm(const void* __restrict__ zraw,
                                              const short* __restrict__ whip,
                                              const short* __restrict__ wlop,
                                              const float* __restrict__ b2g,
                                              unsigned short* __restrict__ hb){
    __shared__ short whi[DIM * WS2];
    __shared__ short wlo[DIM * WS2];
    __shared__ float b2s[DIM];
    int tid = threadIdx.x;

    int lane = tid & 63;
    int wv   = tid >> 6;
    int m = lane & 15;
    int q = lane >> 4;
    int row0 = blockIdx.x * 64 + wv * 16;
    int arow = row0 + m;
    bool avalid = arow < N_NODES;

    f32x4 acc[8];
    #pragma unroll
    for (int t = 0; t < 8; t++) acc[t] = (f32x4){0.f, 0.f, 0.f, 0.f};

    int cs = tid >> 1, pp = tid & 1;

    #pragma unroll
    for (int half = 0; half < 2; half++){
        {
            const short8* sh_ = (const short8*)(whip + half*8192 + cs*64 + pp*32);
            const short8* sl_ = (const short8*)(wlop + half*8192 + cs*64 + pp*32);
            short8* dh = (short8*)&whi[cs*WS2 + pp*32];
            short8* dl = (short8*)&wlo[cs*WS2 + pp*32];
            dh[0] = sh_[0]; dh[1] = sh_[1]; dh[2] = sh_[2]; dh[3] = sh_[3];
            dl[0] = sl_[0]; dl[1] = sl_[1]; dl[2] = sl_[2]; dl[3] = sl_[3];
            if (half == 0 && tid < DIM) b2s[tid] = b2g[tid];
        }
        __syncthreads();

        #pragma unroll
        for (int gl2 = 0; gl2 < 2; gl2++){
            int gg = half*2 + gl2;
            short8 a = {0,0,0,0,0,0,0,0};
            if (avalid){
                if (MODE == 0){
                    const float* xp = (const float*)zraw + (size_t)arow*DIM + gg*32 + q*8;
                    float4 v0 = *(const float4*)xp;
                    float4 v1 = *(const float4*)(xp + 4);
                    a[0] = (short)f2bf(v0.x); a[1] = (short)f2bf(v0.y);
                    a[2] = (short)f2bf(v0.z); a[3] = (short)f2bf(v0.w);
                    a[4] = (short)f2bf(v1.x); a[5] = (short)f2bf(v1.y);
                    a[6] = (short)f2bf(v1.z); a[7] = (short)f2bf(v1.w);
                } else {
                    a = *(const short8*)((const unsigned short*)zraw
                          + (size_t)gg*N_NODES*32 + (size_t)arow*32 + q*8);
                }
            }
            #pragma unroll
            for (int t = 0; t < 8; t++){
                int col = t*16 + m;
                int off = col*WS2 + gl2*32 + q*8;
                short8 bh = *(const short8*)&whi[off];
                short8 bl = *(const short8*)&wlo[off];
                acc[t] = __builtin_amdgcn_mfma_f32_16x16x32_bf16(a, bh, acc[t], 0, 0, 0);
                acc[t] = __builtin_amdgcn_mfma_f32_16x16x32_bf16(a, bl, acc[t], 0, 0, 0);
            }
        }
        if (half == 0) __syncthreads();
    }

    #pragma unroll
    for (int t = 0; t < 8; t++){
        int colg = t*16 + m;
        float bz = b2s[colg];
        size_t base = (size_t)(t >> 1)*N_NODES*32 + (t & 1)*16 + m;
        #pragma unroll
        for (int r = 0; r < 4; r++){
            int row = row0 + q*4 + r;
            if (row < N_NODES)
                hb[base + (size_t)row*32] = f2bf(acc[t][r] + bz);
        }
    }
}

__global__ __launch_bounds__(256) void k_agg(const unsigned short* __restrict__ h,
                                             const int* __restrict__ rowptr,
                                             const int2* __restrict__ epair,
                                             const float* __restrict__ dis,
                                             const float* __restrict__ bias,
                                             unsigned short* __restrict__ out,
                                             float* __restrict__ stats){
    int lane = threadIdx.x & 63;
    int w    = threadIdx.x >> 6;
    int g    = blockIdx.x & 3;
    int sub  = lane >> 4;
    int cp   = lane & 15;
    int cp4  = cp * 4;
    const char* hgb = (const char*)(h + (size_t)g * N_NODES * 32);
    ushort2* og = (ushort2*)(out + (size_t)g * N_NODES * 32);
    float b0 = bias[g*32 + 2*cp], b1 = bias[g*32 + 2*cp + 1];
    float s0 = 0.f, s1 = 0.f, q0 = 0.f, q1 = 0.f;
    int bg = blockIdx.x >> 2;
    int nstride = (gridDim.x >> 2) * 4;

    int node = bg*4 + w;
    int e0 = 0, e1 = 0;
    ushort2 hv; hv.x = 0; hv.y = 0;
    float di = 0.f;
    P4 P = {{0,0},{0,0},{0,0},{0,0}};
    ushort2 X0 = {0,0}, X1 = {0,0}, X2 = {0,0}, X3 = {0,0};
    if (node < N_NODES){
        e0 = rowptr[node];
        e1 = rowptr[node + 1];
        hv = *(const ushort2*)(hgb + (size_t)node*64 + cp4);
        di = dis[node];
        P  = loadP(epair, e0, sub, e1);
        X0 = *(const ushort2*)(hgb + P.a.x + cp4);
        X1 = *(const ushort2*)(hgb + P.b.x + cp4);
        X2 = *(const ushort2*)(hgb + P.c.x + cp4);
        X3 = *(const ushort2*)(hgb + P.d.x + cp4);
    }

    while (node < N_NODES){
        int nnext = node + nstride;
        int ne0 = 0, ne1 = 0;
        ushort2 nhv; nhv.x = 0; nhv.y = 0;
        float ndi = 0.f;
        if (nnext < N_NODES){
            ne0 = rowptr[nnext];
            ne1 = rowptr[nnext + 1];
            nhv = *(const ushort2*)(hgb + (size_t)nnext*64 + cp4);
            ndi = dis[nnext];
        }

        float pa0 = 0.f, pa1 = 0.f, pb0 = 0.f, pb1 = 0.f;
        float pc0 = 0.f, pc1 = 0.f, pd0 = 0.f, pd1 = 0.f;
        if (sub == 0){
            float dii = di * di;
            pa0 = bf2f(hv.x) * dii; pa1 = bf2f(hv.y) * dii;
        }
        {
            float w0 = __int_as_float(P.a.y), w1 = __int_as_float(P.b.y);
            float w2 = __int_as_float(P.c.y), w3 = __int_as_float(P.d.y);
            pa0 = fmaf(bf2f(X0.x), w0, pa0); pa1 = fmaf(bf2f(X0.y), w0, pa1);
            pb0 = fmaf(bf2f(X1.x), w1, pb0); pb1 = fmaf(bf2f(X1.y), w1, pb1);
            pc0 = fmaf(bf2f(X2.x), w2, pc0); pc1 = fmaf(bf2f(X2.y), w2, pc1);
            pd0 = fmaf(bf2f(X3.x), w3, pd0); pd1 = fmaf(bf2f(X3.y), w3, pd1);
        }

        P4 nP = {{0,0},{0,0},{0,0},{0,0}};
        if (nnext < N_NODES) nP = loadP(epair, ne0, sub, ne1);

        for (int e = e0 + 16; e < e1; e += 16){
            P4 Q = loadP(epair, e, sub, e1);
            ushort2 Y0 = *(const ushort2*)(hgb + Q.a.x + cp4);
            ushort2 Y1 = *(const ushort2*)(hgb + Q.b.x + cp4);
            ushort2 Y2 = *(const ushort2*)(hgb + Q.c.x + cp4);
            ushort2 Y3 = *(const ushort2*)(hgb + Q.d.x + cp4);
            float w0 = __int_as_float(Q.a.y), w1 = __int_as_float(Q.b.y);
            float w2 = __int_as_float(Q.c.y), w3 = __int_as_float(Q.d.y);
            pa0 = fmaf(bf2f(Y0.x), w0, pa0); pa1 = fmaf(bf2f(Y0.y), w0, pa1);
            pb0 = fmaf(bf2f(Y1.x), w1, pb0); pb1 = fmaf(bf2f(Y1.y), w1, pb1);
            pc0 = fmaf(bf2f(Y2.x), w2, pc0); pc1 = fmaf(bf2f(Y2.y), w2, pc1);
            pd0 = fmaf(bf2f(Y3.x), w3, pd0); pd1 = fmaf(bf2f(Y3.y), w3, pd1);
        }

        float r0 = (pa0 + pb0) + (pc0 + pd0);
        float r1 = (pa1 + pb1) + (pc1 + pd1);
        r0 += __shfl_xor(r0, 16); r1 += __shfl_xor(r1, 16);
        r0 += __shfl_xor(r0, 32); r1 += __shfl_xor(r1, 32);

        ushort2 nX0 = {0,0}, nX1 = {0,0}, nX2 = {0,0}, nX3 = {0,0};
        if (nnext < N_NODES){
            nX0 = *(const ushort2*)(hgb + nP.a.x + cp4);
            nX1 = *(const ushort2*)(hgb + nP.b.x + cp4);
            nX2 = *(const ushort2*)(hgb + nP.c.x + cp4);
            nX3 = *(const ushort2*)(hgb + nP.d.x + cp4);
        }

        if (sub == 0){
            float a0 = fmaxf(r0 + b0, 0.f);
            float a1 = fmaxf(r1 + b1, 0.f);
            ushort2 ov; ov.x = f2bf(a0); ov.y = f2bf(a1);
            og[node*16 + cp] = ov;
            s0 += a0; s1 += a1; q0 += a0*a0; q1 += a1*a1;
        }

        e0 = ne0; e1 = ne1; hv = nhv; di = ndi;
        P = nP;
        X0 = nX0; X1 = nX1; X2 = nX2; X3 = nX3;
        node = nnext;
    }

    __shared__ float red[4][16][4];
    if (sub == 0){
        red[w][cp][0] = s0; red[w][cp][1] = s1;
        red[w][cp][2] = q0; red[w][cp][3] = q1;
    }
    __syncthreads();
    if (w == 0 && sub == 0){
        #pragma unroll
        for (int ww = 1; ww < 4; ww++){
            s0 += red[ww][cp][0]; s1 += red[ww][cp][1];
            q0 += red[ww][cp][2]; q1 += red[ww][cp][3];
        }
        int c = g*32 + 2*cp;
        atomicAdd(&stats[c],         s0);
        atomicAdd(&stats[c + 1],     s1);
        atomicAdd(&stats[DIM + c],     q0);
        atomicAdd(&stats[DIM + c + 1], q1);
    }
}

__global__ __launch_bounds__(256) void k_bn(const uint4* __restrict__ in,
                                            const float* __restrict__ stats,
                                            const float* __restrict__ gamma,
                                            const float* __restrict__ beta,
                                            float4* __restrict__ outf){
    __shared__ float scs[DIM], shs[DIM];
    int tid = threadIdx.x;
    if (tid < DIM){
        float mu  = stats[tid] * (1.0f / N_NODES);
        float var = stats[DIM + tid] * (1.0f / N_NODES) - mu * mu;
        float sc  = rsqrtf(var + BN_EPS) * gamma[tid];
        scs[tid] = sc;
        shs[tid] = beta[tid] - mu * sc;
    }
    __syncthreads();

    int i = blockIdx.x * 256 + tid;
    if (i >= N_NODES * DIM / 8) return;
    int row = i >> 4;
    int c = (i * 8) & (DIM - 1);
    int gg = c >> 5, wi = c & 31;
    uint4 raw = in[gg*(N_NODES*4) + row*4 + (wi >> 3)];
    unsigned int u[4] = {raw.x, raw.y, raw.z, raw.w};
    float v[8];
    #pragma unroll
    for (int j = 0; j < 4; j++){
        v[2*j]   = bf2f((unsigned short)(u[j] & 0xffff));
        v[2*j+1] = bf2f((unsigned short)(u[j] >> 16));
    }
    float4 r0, r1;
    r0.x = fmaf(v[0], scs[c+0], shs[c+0]);
    r0.y = fmaf(v[1], scs[c+1], shs[c+1]);
    r0.z = fmaf(v[2], scs[c+2], shs[c+2]);
    r0.w = fmaf(v[3], scs[c+3], shs[c+3]);
    r1.x = fmaf(v[4], scs[c+4], shs[c+4]);
    r1.y = fmaf(v[5], scs[c+5], shs[c+5]);
    r1.z = fmaf(v[6], scs[c+6], shs[c+6]);
    r1.w = fmaf(v[7], scs[c+7], shs[c+7]);
    outf[2*i]   = r0;
    outf[2*i+1] = r1;
}

extern "C" void kernel_launch(void* const* d_in, const int* in_sizes, int n_in,
                              void* d_out, int out_size, void* d_ws, size_t ws_size,
                              hipStream_t stream){
    const float* x   = (const float*)d_in[0];
    const int*   src = (const int*)d_in[1];
    const int*   dst = src + N_EDGES;
    const float* Ws  = (const float*)d_in[2];
    const float* bs  = (const float*)d_in[3];
    const float* gs  = (const float*)d_in[4];
    const float* be  = (const float*)d_in[5];

    char* w = (char*)d_ws;
    int*   degcnt = (int*)(w);
    short* whip   = (short*)(w);
    short* wlop   = (short*)(w + 32768);
    float* b2g    = (float*)(w + 65536);
    float* stats  = (float*)(w + 200000);
    float* dis    = (float*)(w + 208192);
    int*   rowptr = (int*)(w + 408192);
    int*   wptr   = (int*)(w + 608208);
    int*   bsum   = (int*)(w + 808208);
    int2*  epair  = (int2*)(w + 875280);
    unsigned short* bufA = (unsigned short*)(w + 7275280);
    unsigned short* hb   = (unsigned short*)(w + 20075280);

    k_zero<<<(51024 + 255)/256, 256, 0, stream>>>(degcnt, 51024);
    k_count<<<3125, 256, 0, stream>>>(dst, degcnt);
    k_scan1<<<SCAN_BLOCKS, 256, 0, stream>>>(degcnt, rowptr, bsum, dis);
    k_scan3<<<SCAN_BLOCKS, 256, 0, stream>>>(bsum, rowptr, wptr);
    k_fill<<<3125, 256, 0, stream>>>(src, dst, dis, wptr, epair);

    for (int L = 0; L < NLAYERS; L++){
        const float* Wl = Ws + L*DIM*DIM;
        if (L == 0){
            k_wprep<0><<<17, 256, 0, stream>>>(Wl, nullptr, nullptr, nullptr,
                                               whip, wlop, b2g);
            k_gemm<0><<<(N_NODES + 63)/64, 256, 0, stream>>>(x, whip, wlop,
                                               b2g, hb);
        } else {
            k_wprep<1><<<17, 256, 0, stream>>>(Wl, stats + (L-1)*256,
                                               gs + (L-1)*DIM, be + (L-1)*DIM,
                                               whip, wlop, b2g);
            k_gemm<1><<<(N_NODES + 63)/64, 256, 0, stream>>>(bufA, whip, wlop,
                                               b2g, hb);
        }
        k_agg<<<2048, 256, 0, stream>>>(hb, rowptr, epair, dis, bs + L*DIM,
                                        bufA, stats + L*256);
    }
    k_bn<<<3125, 256, 0, stream>>>((const uint4*)bufA, stats + 3*256,
                                   gs + 3*DIM, be + 3*DIM, (float4*)d_out);
}